// Round 6
// baseline (470.285 us; speedup 1.0000x reference)
//
#include <hip/hip_runtime.h>

#define DM 256
#define NOUT 768
#define JOINTS 22
#define MROWS 44            // 2 frames per block (44 % 22 == 0)
#define NBLK 2048           // 90112 / 44
#define QKSTR 40            // q_s/k_s row stride in shorts (80 B: 16B-aligned, bank-spread)

typedef __attribute__((ext_vector_type(8))) short bf16x8;
typedef __attribute__((ext_vector_type(4))) float f32x4;

__device__ __forceinline__ float b2f(unsigned short u) {
    union { unsigned int i; float f; } x; x.i = ((unsigned int)u) << 16; return x.f;
}
__device__ __forceinline__ unsigned short f2b(float f) {
    union { float f; unsigned int u; } x; x.f = f;
    unsigned int r = x.u + 0x7FFFu + ((x.u >> 16) & 1u);
    return (unsigned short)(r >> 16);
}

// ws layout
#define OFF_PEWB 0
#define OFF_WCAN (JOINTS * NOUT * 4)                 // 67584

// ---------------- convert W (fp32 -> bf16), 3 matrices ----------------
__global__ __launch_bounds__(256) void wconv_kernel(const float* __restrict__ w0,
                                                    const float* __restrict__ w1,
                                                    const float* __restrict__ w2,
                                                    unsigned short* __restrict__ wcan)
{
    const float* w = (blockIdx.y == 0) ? w0 : (blockIdx.y == 1 ? w1 : w2);
    int i = (blockIdx.x * 256 + threadIdx.x) * 8;
    const float* s = w + i;
    union { uint4 v; float f[4]; } a, b;
    a.v = *(const uint4*)(s);
    b.v = *(const uint4*)(s + 4);
    union { uint4 v; unsigned short u[8]; } o;
    #pragma unroll
    for (int k = 0; k < 4; ++k) { o.u[k] = f2b(a.f[k]); o.u[4 + k] = f2b(b.f[k]); }
    *(uint4*)(wcan + blockIdx.y * (DM * DM) + i) = o.v;
}

// ---------------- PEWB[j,e] = bias[e] + sum_d pe[j,d] * W[e,d]  (fp32) ----------------
__global__ __launch_bounds__(256) void pewb_kernel(const float* __restrict__ wq,
                                                   const float* __restrict__ wk,
                                                   const float* __restrict__ wv,
                                                   const float* __restrict__ bq,
                                                   const float* __restrict__ bk,
                                                   const float* __restrict__ bv,
                                                   float* __restrict__ pewb)
{
    __shared__ float pe_s[DM];
    const int j   = blockIdx.x / 3;
    const int mat = blockIdx.x % 3;
    const int t = threadIdx.x;
    {
        int i = t >> 1;
        float div = __expf((float)(2 * i) * (-9.210340371976184f / 256.0f)); // -ln(10000)/256
        float ang = (float)j * div;
        pe_s[t] = (t & 1) ? cosf(ang) : sinf(ang);
    }
    __syncthreads();
    const float* w  = (mat == 0) ? wq : (mat == 1 ? wk : wv);
    const float* bb = (mat == 0) ? bq : (mat == 1 ? bk : bv);
    float acc = bb[t];
    const float* wr = w + (size_t)t * DM;
    #pragma unroll 8
    for (int d = 0; d < DM; ++d) acc += pe_s[d] * wr[d];
    pewb[j * NOUT + mat * DM + t] = acc;
}

// ---------------- fused QKV-GEMM + MFMA block-diagonal attention ----------------
// One block = 44 tokens (2 frames), 256 threads (4 waves). Per iter (2 heads):
// MFMA GEMM (48x192x256, W from L2, wave owns 48 N-cols x all 3 M-tiles) ->
// epilogue (+PEWB, Q pre-scaled 1/sqrt(32)) -> LDS Q,K (stride 40: bank-spread)
// + V^T ([hl][fr][d][k] stride 24, pad zeroed) -> wave = (frame, head) MFMA attn.
// 4-wave blocks: at 128 VGPR the HW fits 3 waves/SIMD; 8-wave blocks quantized
// to ONE resident block (occ 23%, rounds 3/5). 42.8 KB LDS -> 3 blocks/CU.
__global__ __launch_bounds__(256, 4) void fused_kernel(const float* __restrict__ x,
                                                       const unsigned short* __restrict__ wcan,
                                                       const float* __restrict__ pewb,
                                                       float* __restrict__ out)
{
    __shared__ __align__(16) unsigned short xs[MROWS * 256];          // 22528 B, chunk-swizzled
    __shared__ __align__(16) unsigned short q_s[2 * MROWS * QKSTR];   // 7040 B
    __shared__ __align__(16) unsigned short k_s[2 * MROWS * QKSTR];   // 7040 B
    __shared__ __align__(16) unsigned short v_t[2 * 2 * 32 * 24 + 8]; // 6160 B (pad for b128 tail)

    const int t    = threadIdx.x;
    const int tok0 = blockIdx.x * MROWS;

    // ---- stage x tile fp32 -> bf16, swizzled (chunk c at (c&24)|((c&7)^(row&7))) ----
    for (int i = t; i < MROWS * 32; i += 256) {
        int row = i >> 5, c = i & 31;
        const float* src = x + (size_t)(tok0 + row) * DM + c * 8;
        union { uint4 v; float f[4]; } a, b;
        a.v = *(const uint4*)(src);
        b.v = *(const uint4*)(src + 4);
        union { uint4 v; unsigned short u[8]; } o;
        #pragma unroll
        for (int k = 0; k < 4; ++k) { o.u[k] = f2b(a.f[k]); o.u[4 + k] = f2b(b.f[k]); }
        int cs = (c & 24) | ((c & 7) ^ (row & 7));
        *(uint4*)(&xs[row * 256 + cs * 8]) = o.v;
    }
    // one-time zero of v_t (k-pad lanes 22/23 are never written by the epilogue)
    {
        unsigned int* vz = (unsigned int*)v_t;
        for (int i = t; i < (2 * 2 * 32 * 24 + 8) / 2; i += 256) vz[i] = 0u;
    }
    __syncthreads();

    const int lane = t & 63;
    const int wave = t >> 6;               // 0..3
    const int wn   = wave * 48;            // N wave-group: cols [wn, wn+48) of 192
    const int lrow = lane & 15;
    const int quad = lane >> 4;

    // A-fragment row indices (M padded 44->48: clamp, results masked at store)
    int abase[3], axor[3];
    #pragma unroll
    for (int mi = 0; mi < 3; ++mi) {
        int ar = mi * 16 + lrow;
        if (ar > MROWS - 1) ar = MROWS - 1;
        abase[mi] = ar * 256;
        axor[mi]  = ar & 7;
    }

    #pragma unroll 1
    for (int it = 0; it < 4; ++it) {
        const int h0 = it * 2;

        // B row pointers: col n of this iter -> W row. n: mat=n>>6, hl=(n>>5)&1, d=n&31
        const unsigned short* bp[3];
        #pragma unroll
        for (int ni = 0; ni < 3; ++ni) {
            int n   = wn + ni * 16 + lrow;
            int mat = n >> 6;
            int e   = (h0 + ((n >> 5) & 1)) * 32 + (n & 31);
            bp[ni] = wcan + mat * (DM * DM) + (size_t)e * DM + quad * 8;
        }

        f32x4 acc[3][3];
        #pragma unroll
        for (int mi = 0; mi < 3; ++mi)
            #pragma unroll
            for (int ni = 0; ni < 3; ++ni)
                acc[mi][ni] = (f32x4){0.f, 0.f, 0.f, 0.f};

        auto kstep = [&](int kk, bf16x8* breg) {
            bf16x8 a[3];
            int c = (kk >> 3) + quad;
            #pragma unroll
            for (int mi = 0; mi < 3; ++mi) {
                int cs = (c & 24) | ((c & 7) ^ axor[mi]);
                a[mi] = *(const bf16x8*)(&xs[abase[mi] + cs * 8]);
            }
            #pragma unroll
            for (int mi = 0; mi < 3; ++mi)
                #pragma unroll
                for (int ni = 0; ni < 3; ++ni)
                    acc[mi][ni] = __builtin_amdgcn_mfma_f32_16x16x32_bf16(
                        a[mi], breg[ni], acc[mi][ni], 0, 0, 0);
        };

        bf16x8 bA[3], bB[3];
        #pragma unroll
        for (int ni = 0; ni < 3; ++ni) bA[ni] = *(const bf16x8*)(bp[ni]);
        #pragma unroll 1
        for (int kk = 0; kk < 192; kk += 64) {
            #pragma unroll
            for (int ni = 0; ni < 3; ++ni) bB[ni] = *(const bf16x8*)(bp[ni] + kk + 32);
            kstep(kk, bA);
            #pragma unroll
            for (int ni = 0; ni < 3; ++ni) bA[ni] = *(const bf16x8*)(bp[ni] + kk + 64);
            kstep(kk + 32, bB);
        }
        #pragma unroll
        for (int ni = 0; ni < 3; ++ni) bB[ni] = *(const bf16x8*)(bp[ni] + 224);
        kstep(192, bA);
        kstep(224, bB);

        __syncthreads();   // previous iter's attn readers are done with q/k/v LDS

        // ---- epilogue: + PEWB[joint]; Q scaled by 1/sqrt(32); V stored transposed ----
        #pragma unroll
        for (int ni = 0; ni < 3; ++ni) {
            int n   = wn + ni * 16 + lrow;
            int mat = n >> 6;            // wave-uniform per ni (16-aligned slices)
            int hl2 = (n >> 5) & 1;
            int d   = n & 31;
            int pcol = mat * 256 + (h0 + hl2) * 32 + d;
            #pragma unroll
            for (int mi = 0; mi < 3; ++mi) {
                int rbase = mi * 16 + quad * 4;   // C row = quad*4 + reg
                if (rbase < MROWS) {
                    #pragma unroll
                    for (int rg = 0; rg < 4; ++rg) {
                        int r = rbase + rg;
                        int joint = r % 22;            // tok0 % 22 == 0
                        float val = acc[mi][ni][rg] + pewb[joint * NOUT + pcol];
                        if (mat == 0) {
                            q_s[(hl2 * MROWS + r) * QKSTR + d] = f2b(val * 0.17677669529663688f);
                        } else if (mat == 1) {
                            k_s[(hl2 * MROWS + r) * QKSTR + d] = f2b(val);
                        } else {
                            int frr = r / 22;
                            v_t[((hl2 * 2 + frr) * 32 + d) * 24 + joint] = f2b(val);
                        }
                    }
                }
            }
        }
        __syncthreads();

        // ---- MFMA attention: wave = (frame, local head); 2 frames x 2 heads = 4 waves ----
        {
            const int fr2  = wave >> 1;
            const int hl2  = wave & 1;
            const int rowb = hl2 * MROWS + fr2 * 22;

            // S^T[k,q] = sum_d K[k,d] Q[q,d]: A = K rows, B = Q rows (both lrow-indexed)
            bf16x8 ka[2], qb[2];
            #pragma unroll
            for (int km = 0; km < 2; ++km) {
                int kr = km * 16 + lrow; if (kr > 21) kr = 21;
                ka[km] = *(const bf16x8*)(&k_s[(rowb + kr) * QKSTR + quad * 8]);
            }
            #pragma unroll
            for (int qn = 0; qn < 2; ++qn) {
                int qr = qn * 16 + lrow; if (qr > 21) qr = 21;
                qb[qn] = *(const bf16x8*)(&q_s[(rowb + qr) * QKSTR + quad * 8]);
            }
            f32x4 st[2][2];
            #pragma unroll
            for (int km = 0; km < 2; ++km)
                #pragma unroll
                for (int qn = 0; qn < 2; ++qn)
                    st[km][qn] = __builtin_amdgcn_mfma_f32_16x16x32_bf16(
                        ka[km], qb[qn], (f32x4){0.f, 0.f, 0.f, 0.f}, 0, 0, 0);

            // softmax per q (= lrow of each qn tile); lane holds k = quad*4+r (+16)
            unsigned int u[2][2][2];   // [qn][km][rpair] packed bf16 pairs of P
            #pragma unroll
            for (int qn = 0; qn < 2; ++qn) {
                float mx = -3.0e38f;
                #pragma unroll
                for (int r2 = 0; r2 < 4; ++r2) mx = fmaxf(mx, st[0][qn][r2]);
                #pragma unroll
                for (int r2 = 0; r2 < 4; ++r2)
                    if (16 + quad * 4 + r2 < 22) mx = fmaxf(mx, st[1][qn][r2]);
                mx = fmaxf(mx, __shfl_xor(mx, 16));
                mx = fmaxf(mx, __shfl_xor(mx, 32));
                float p0[4], p1[4];
                float sum = 0.f;
                #pragma unroll
                for (int r2 = 0; r2 < 4; ++r2) { p0[r2] = __expf(st[0][qn][r2] - mx); sum += p0[r2]; }
                #pragma unroll
                for (int r2 = 0; r2 < 4; ++r2) {
                    float e = (16 + quad * 4 + r2 < 22) ? __expf(st[1][qn][r2] - mx) : 0.f;
                    p1[r2] = e; sum += e;
                }
                sum += __shfl_xor(sum, 16);
                sum += __shfl_xor(sum, 32);
                float inv = 1.f / sum;
                #pragma unroll
                for (int r2 = 0; r2 < 4; ++r2) { p0[r2] *= inv; p1[r2] *= inv; }
                u[qn][0][0] = (unsigned int)f2b(p0[0]) | ((unsigned int)f2b(p0[1]) << 16);
                u[qn][0][1] = (unsigned int)f2b(p0[2]) | ((unsigned int)f2b(p0[3]) << 16);
                u[qn][1][0] = (unsigned int)f2b(p1[0]) | ((unsigned int)f2b(p1[1]) << 16);
                u[qn][1][1] = (unsigned int)f2b(p1[2]) | ((unsigned int)f2b(p1[3]) << 16);
            }

            // repack P (C layout) -> A-frag layout: target k = quad*8 + 2j + {0,1};
            // source lane = lrow + 16*((quad&1)*2 + (j>>1)), km = quad>>1, rp = j&1.
            bf16x8 pa[2];
            #pragma unroll
            for (int qm = 0; qm < 2; ++qm) {
                union { bf16x8 v; unsigned int w[4]; } au;
                #pragma unroll
                for (int j = 0; j < 4; ++j) {
                    int src = lrow + 16 * ((quad & 1) * 2 + (j >> 1));
                    unsigned int lo = (unsigned int)__shfl((int)u[qm][0][j & 1], src, 64);
                    unsigned int hi = (unsigned int)__shfl((int)u[qm][1][j & 1], src, 64);
                    au.w[j] = (quad < 2) ? lo : hi;
                }
                pa[qm] = au.v;
            }

            // O[q,d] = P x V: B-frag from V^T rows (d = lrow), k = quad*8+e (pad reads
            // land in the zeroed stride-24 tail / next rows; P there is exactly 0)
            bf16x8 vb[2];
            #pragma unroll
            for (int dn = 0; dn < 2; ++dn)
                vb[dn] = *(const bf16x8*)(&v_t[((hl2 * 2 + fr2) * 32 + dn * 16 + lrow) * 24 + quad * 8]);

            f32x4 ot[2][2];
            #pragma unroll
            for (int qm = 0; qm < 2; ++qm)
                #pragma unroll
                for (int dn = 0; dn < 2; ++dn)
                    ot[qm][dn] = __builtin_amdgcn_mfma_f32_16x16x32_bf16(
                        pa[qm], vb[dn], (f32x4){0.f, 0.f, 0.f, 0.f}, 0, 0, 0);

            #pragma unroll
            for (int qm = 0; qm < 2; ++qm) {
                #pragma unroll
                for (int r2 = 0; r2 < 4; ++r2) {
                    int q = qm * 16 + quad * 4 + r2;
                    if (q < 22) {
                        float* op = out + (size_t)(tok0 + fr2 * 22 + q) * DM + (h0 + hl2) * 32;
                        op[lrow]      = ot[qm][0][r2];
                        op[16 + lrow] = ot[qm][1][r2];
                    }
                }
            }
        }
        // no barrier here: next iter's pre-epilogue barrier protects q/k/v/v_t.
    }
}

extern "C" void kernel_launch(void* const* d_in, const int* in_sizes, int n_in,
                              void* d_out, int out_size, void* d_ws, size_t ws_size,
                              hipStream_t stream) {
    const float* x  = (const float*)d_in[0];
    const float* wq = (const float*)d_in[1];
    const float* bq = (const float*)d_in[2];
    const float* wk = (const float*)d_in[3];
    const float* bk = (const float*)d_in[4];
    const float* wv = (const float*)d_in[5];
    const float* bv = (const float*)d_in[6];

    char* ws = (char*)d_ws;
    float*          pewb = (float*)(ws + OFF_PEWB);
    unsigned short* wcan = (unsigned short*)(ws + OFF_WCAN);

    wconv_kernel<<<dim3(32, 3), dim3(256), 0, stream>>>(wq, wk, wv, wcan);
    pewb_kernel<<<dim3(66), dim3(256), 0, stream>>>(wq, wk, wv, bq, bk, bv, pewb);
    fused_kernel<<<dim3(NBLK), dim3(256), 0, stream>>>(x, wcan, pewb, (float*)d_out);
}

// Round 7
// 342.922 us; speedup vs baseline: 1.3714x; 1.3714x over previous
//
#include <hip/hip_runtime.h>

#define TOKENS 90112
#define DM 256
#define NOUT 768
#define JOINTS 22

typedef __attribute__((ext_vector_type(8))) short bf16x8;
typedef __attribute__((ext_vector_type(4))) float f32x4;

__device__ __forceinline__ float b2f(unsigned short u) {
    union { unsigned int i; float f; } x; x.i = ((unsigned int)u) << 16; return x.f;
}
__device__ __forceinline__ unsigned short f2b(float f) {
    union { float f; unsigned int u; } x; x.f = f;
    unsigned int r = x.u + 0x7FFFu + ((x.u >> 16) & 1u);
    return (unsigned short)(r >> 16);
}

// ws layout
#define OFF_PEWB 0
#define OFF_WCAN (JOINTS * NOUT * 4)                 // 67584
#define OFF_QKV  (OFF_WCAN + 3 * DM * DM * 2)        // 460800

// ---------------- convert W (fp32 -> bf16), 3 matrices ----------------
__global__ __launch_bounds__(256) void wconv_kernel(const float* __restrict__ w0,
                                                    const float* __restrict__ w1,
                                                    const float* __restrict__ w2,
                                                    unsigned short* __restrict__ wcan)
{
    const float* w = (blockIdx.y == 0) ? w0 : (blockIdx.y == 1 ? w1 : w2);
    int i = (blockIdx.x * 256 + threadIdx.x) * 8;
    const float* s = w + i;
    union { uint4 v; float f[4]; } a, b;
    a.v = *(const uint4*)(s);
    b.v = *(const uint4*)(s + 4);
    union { uint4 v; unsigned short u[8]; } o;
    #pragma unroll
    for (int k = 0; k < 4; ++k) { o.u[k] = f2b(a.f[k]); o.u[4 + k] = f2b(b.f[k]); }
    *(uint4*)(wcan + blockIdx.y * (DM * DM) + i) = o.v;
}

// ---------------- PEWB[j,e] = bias[e] + sum_d pe[j,d] * W[e,d]  (fp32) ----------------
__global__ __launch_bounds__(256) void pewb_kernel(const float* __restrict__ wq,
                                                   const float* __restrict__ wk,
                                                   const float* __restrict__ wv,
                                                   const float* __restrict__ bq,
                                                   const float* __restrict__ bk,
                                                   const float* __restrict__ bv,
                                                   float* __restrict__ pewb)
{
    __shared__ float pe_s[DM];
    const int j   = blockIdx.x / 3;
    const int mat = blockIdx.x % 3;
    const int t = threadIdx.x;
    {
        int i = t >> 1;
        float div = __expf((float)(2 * i) * (-9.210340371976184f / 256.0f)); // -ln(10000)/256
        float ang = (float)j * div;
        pe_s[t] = (t & 1) ? cosf(ang) : sinf(ang);
    }
    __syncthreads();
    const float* w  = (mat == 0) ? wq : (mat == 1 ? wk : wv);
    const float* bb = (mat == 0) ? bq : (mat == 1 ? bk : bv);
    float acc = bb[t];
    const float* wr = w + (size_t)t * DM;
    #pragma unroll 8
    for (int d = 0; d < DM; ++d) acc += pe_s[d] * wr[d];
    pewb[j * NOUT + mat * DM + t] = acc;
}

// ---------------- QKV GEMM: r0 structure + double-buffered Bs (1 barrier/K-chunk) ----------------
#define BM 64
#define BN 128

__global__ __launch_bounds__(256) void qkv_gemm(const float* __restrict__ x,
                                                const unsigned short* __restrict__ wcan,
                                                const float* __restrict__ pewb,
                                                unsigned short* __restrict__ qkv)
{
    __shared__ __align__(16) unsigned short As[BM * 256];     // 32 KB, chunk-swizzled
    __shared__ __align__(16) unsigned short Bs[2][BN * 64];   // 2 x 16 KB

    const int t    = threadIdx.x;
    const int m0   = blockIdx.x * BM;
    const int lane = t & 63;
    const int wave = t >> 6;
    const int wm   = (wave & 1) * 32;
    const int wn   = (wave >> 1) * 64;
    const int lrow = lane & 15;
    const int quad = lane >> 4;

    // stage full-K x tile, converting fp32 -> bf16 (8 chunks of 8 per thread)
    #pragma unroll
    for (int i = 0; i < 8; ++i) {
        int ch  = t + i * 256;          // 0..2047
        int row = ch >> 5, c = ch & 31;
        const float* src = x + (size_t)(m0 + row) * DM + c * 8;
        union { uint4 v; float f[4]; } a, b;
        a.v = *(const uint4*)(src);
        b.v = *(const uint4*)(src + 4);
        union { uint4 v; unsigned short u[8]; } o;
        #pragma unroll
        for (int k = 0; k < 4; ++k) { o.u[k] = f2b(a.f[k]); o.u[4 + k] = f2b(b.f[k]); }
        int cs = (c & 24) | ((c & 7) ^ (row & 7));
        *(uint4*)(&As[row * 256 + cs * 8]) = o.v;
    }

    // prologue: stage Bs[0] for bn=0, k0=0
    #pragma unroll
    for (int i = 0; i < 4; ++i) {
        int ch = t + i * 256;           // 0..1023
        int row = ch >> 3, c = ch & 7;
        uint4 v = *(const uint4*)(&wcan[(size_t)row * DM + c * 8]);
        *(uint4*)(&Bs[0][row * 64 + ((c ^ (row & 7)) * 8)]) = v;
    }
    __syncthreads();

    #pragma unroll 1
    for (int bn = 0; bn < 6; ++bn) {
        const unsigned short* wbase = wcan + (bn >> 1) * (DM * DM) + (bn & 1) * (BN * DM);

        f32x4 acc[2][4];
        #pragma unroll
        for (int mi = 0; mi < 2; ++mi)
            #pragma unroll
            for (int ni = 0; ni < 4; ++ni)
                acc[mi][ni] = (f32x4){0.f, 0.f, 0.f, 0.f};

        #pragma unroll 1
        for (int k0i = 0; k0i < 4; ++k0i) {
            const int cur = k0i & 1;
            const bool pf = (k0i < 3) || (bn < 5);
            const unsigned short* wpf = (k0i < 3) ? wbase
                : (wcan + ((bn + 1) >> 1) * (DM * DM) + ((bn + 1) & 1) * (BN * DM));
            const int kpf = (k0i < 3) ? (k0i + 1) * 64 : 0;

            uint4 pr[4];
            if (pf) {
                #pragma unroll
                for (int i = 0; i < 4; ++i) {
                    int ch = t + i * 256;
                    int row = ch >> 3, c = ch & 7;
                    pr[i] = *(const uint4*)(&wpf[(size_t)row * DM + kpf + c * 8]);
                }
            }

            // compute 2 ksteps from Bs[cur]
            #pragma unroll
            for (int kk2 = 0; kk2 < 2; ++kk2) {
                bf16x8 a[2], b[4];
                #pragma unroll
                for (int mi = 0; mi < 2; ++mi) {
                    int row = wm + mi * 16 + lrow;
                    int c   = ((k0i * 64 + kk2 * 32) >> 3) + quad;
                    int cs  = (c & 24) | ((c & 7) ^ (row & 7));
                    a[mi] = *(const bf16x8*)(&As[row * 256 + cs * 8]);
                }
                #pragma unroll
                for (int ni = 0; ni < 4; ++ni) {
                    int row = wn + ni * 16 + lrow;
                    int cb  = kk2 * 4 + quad;
                    b[ni] = *(const bf16x8*)(&Bs[cur][row * 64 + ((cb ^ (row & 7)) * 8)]);
                }
                #pragma unroll
                for (int mi = 0; mi < 2; ++mi)
                    #pragma unroll
                    for (int ni = 0; ni < 4; ++ni)
                        acc[mi][ni] = __builtin_amdgcn_mfma_f32_16x16x32_bf16(
                            a[mi], b[ni], acc[mi][ni], 0, 0, 0);
            }

            if (pf) {
                #pragma unroll
                for (int i = 0; i < 4; ++i) {
                    int ch = t + i * 256;
                    int row = ch >> 3, c = ch & 7;
                    *(uint4*)(&Bs[cur ^ 1][row * 64 + ((c ^ (row & 7)) * 8)]) = pr[i];
                }
            }
            __syncthreads();
        }

        // epilogue: add PEWB[joint], store bf16
        const int n0 = bn * BN;
        #pragma unroll
        for (int mi = 0; mi < 2; ++mi) {
            #pragma unroll
            for (int r = 0; r < 4; ++r) {
                int row   = wm + mi * 16 + quad * 4 + r;   // C row = (lane>>4)*4 + reg
                int token = m0 + row;
                int joint = token % JOINTS;
                const float* pw = pewb + joint * NOUT + n0;
                size_t obase = (size_t)token * NOUT + n0;
                #pragma unroll
                for (int ni = 0; ni < 4; ++ni) {
                    int col = wn + ni * 16 + lrow;         // C col = lane&15
                    qkv[obase + col] = f2b(acc[mi][ni][r] + pw[col]);
                }
            }
        }
    }
}

// ---------------- MFMA block-diagonal attention: block = 44 tokens (2 frames) ----------------
// K staged row-major (stride 40: b128 frags conflict-optimal); V staged transposed
// ([h*2+fr][d:32][k stride 24], r6-proven layout, pad cols 22/23 zeroed); Q fragments
// read straight from global qkv (64B lines fully consumed). Wave-unit = (frame, head):
// S^T = mfma(K,Q) scaled in softmax, in-reg masked softmax (shfl_xor 16/32), P repacked
// via 16 shfls, O = mfma(P, V^T). 52.7 KB LDS -> 3 blocks/CU; low VGPR.
#define ABLK 44

__global__ __launch_bounds__(256) void attn_kernel(const unsigned short* __restrict__ qkv,
                                                   float* __restrict__ out)
{
    __shared__ __align__(16) unsigned short k_s[8 * ABLK * 40];       // 28160 B
    __shared__ __align__(16) unsigned short v_t[16 * 32 * 24 + 8];    // 24592 B

    const int t    = threadIdx.x;
    const int tok0 = blockIdx.x * ABLK;
    const int lane = t & 63;
    const int wave = t >> 6;
    const int lrow = lane & 15;
    const int quad = lane >> 4;

    // zero pad cols (k=22,23) of every v_t row + tail (disjoint from staged cols)
    for (int i = t; i < 16 * 32; i += 256)
        *(unsigned int*)(&v_t[i * 24 + 22]) = 0u;
    if (t < 4) ((unsigned int*)(&v_t[16 * 32 * 24]))[t] = 0u;

    // stage K rows (coalesced 16B chunks)
    for (int i = t; i < ABLK * 32; i += 256) {
        int r = i >> 5;          // token row 0..43
        int c = i & 31;          // 8-short chunk: h = c>>2, dchunk = c&3
        int h = c >> 2, dc = c & 3;
        uint4 v = *(const uint4*)(&qkv[(size_t)(tok0 + r) * NOUT + 256 + c * 8]);
        *(uint4*)(&k_s[(h * ABLK + r) * 40 + dc * 8]) = v;
    }
    // stage V transposed (u16 scatter into v_t[row=d][col=k])
    for (int i = t; i < ABLK * 32; i += 256) {
        int r = i >> 5;
        int c = i & 31;
        int h = c >> 2, dc = c & 3;
        int fr = r / 22, k = r - fr * 22;
        union { uint4 v; unsigned short u[8]; } w;
        w.v = *(const uint4*)(&qkv[(size_t)(tok0 + r) * NOUT + 512 + c * 8]);
        int base = ((h * 2 + fr) * 32 + dc * 8) * 24 + k;
        #pragma unroll
        for (int j = 0; j < 8; ++j) v_t[base + j * 24] = w.u[j];
    }
    __syncthreads();

    const float SC = 0.17677669529663688f;   // 1/sqrt(32)

    #pragma unroll 1
    for (int stp = 0; stp < 4; ++stp) {
        const int u4 = wave + stp * 4;       // 0..15
        const int fr = u4 & 1;
        const int h  = u4 >> 1;

        // S^T[k,q]: A = K rows (LDS), B = Q rows (global)
        bf16x8 ka[2], qb[2];
        #pragma unroll
        for (int km = 0; km < 2; ++km) {
            int kr = km * 16 + lrow; if (kr > 21) kr = 21;
            ka[km] = *(const bf16x8*)(&k_s[(h * ABLK + fr * 22 + kr) * 40 + quad * 8]);
        }
        #pragma unroll
        for (int qn = 0; qn < 2; ++qn) {
            int qr = qn * 16 + lrow; if (qr > 21) qr = 21;
            qb[qn] = *(const bf16x8*)(&qkv[(size_t)(tok0 + fr * 22 + qr) * NOUT + h * 32 + quad * 8]);
        }
        f32x4 st[2][2];
        #pragma unroll
        for (int km = 0; km < 2; ++km)
            #pragma unroll
            for (int qn = 0; qn < 2; ++qn)
                st[km][qn] = __builtin_amdgcn_mfma_f32_16x16x32_bf16(
                    ka[km], qb[qn], (f32x4){0.f, 0.f, 0.f, 0.f}, 0, 0, 0);

        // masked softmax per q (= lrow); lane holds k = km*16 + quad*4 + r2; scale by SC
        unsigned int u[2][2][2];
        #pragma unroll
        for (int qn = 0; qn < 2; ++qn) {
            float mx = -3.0e38f;
            #pragma unroll
            for (int r2 = 0; r2 < 4; ++r2) mx = fmaxf(mx, st[0][qn][r2] * SC);
            #pragma unroll
            for (int r2 = 0; r2 < 4; ++r2)
                if (16 + quad * 4 + r2 < 22) mx = fmaxf(mx, st[1][qn][r2] * SC);
            mx = fmaxf(mx, __shfl_xor(mx, 16));
            mx = fmaxf(mx, __shfl_xor(mx, 32));
            float p0[4], p1[4];
            float sum = 0.f;
            #pragma unroll
            for (int r2 = 0; r2 < 4; ++r2) { p0[r2] = __expf(st[0][qn][r2] * SC - mx); sum += p0[r2]; }
            #pragma unroll
            for (int r2 = 0; r2 < 4; ++r2) {
                float e = (16 + quad * 4 + r2 < 22) ? __expf(st[1][qn][r2] * SC - mx) : 0.f;
                p1[r2] = e; sum += e;
            }
            sum += __shfl_xor(sum, 16);
            sum += __shfl_xor(sum, 32);
            float inv = 1.f / sum;
            #pragma unroll
            for (int r2 = 0; r2 < 4; ++r2) { p0[r2] *= inv; p1[r2] *= inv; }
            u[qn][0][0] = (unsigned int)f2b(p0[0]) | ((unsigned int)f2b(p0[1]) << 16);
            u[qn][0][1] = (unsigned int)f2b(p0[2]) | ((unsigned int)f2b(p0[3]) << 16);
            u[qn][1][0] = (unsigned int)f2b(p1[0]) | ((unsigned int)f2b(p1[1]) << 16);
            u[qn][1][1] = (unsigned int)f2b(p1[2]) | ((unsigned int)f2b(p1[3]) << 16);
        }

        // repack P (C layout) -> A-frag layout (r5/r6-verified)
        bf16x8 pa[2];
        #pragma unroll
        for (int qm = 0; qm < 2; ++qm) {
            union { bf16x8 v; unsigned int w[4]; } au;
            #pragma unroll
            for (int j = 0; j < 4; ++j) {
                int src = lrow + 16 * ((quad & 1) * 2 + (j >> 1));
                unsigned int lo = (unsigned int)__shfl((int)u[qm][0][j & 1], src, 64);
                unsigned int hi = (unsigned int)__shfl((int)u[qm][1][j & 1], src, 64);
                au.w[j] = (quad < 2) ? lo : hi;
            }
            pa[qm] = au.v;
        }

        // O = P x V (V^T frags; pad/overhang reads are finite junk x P=0)
        bf16x8 vb[2];
        #pragma unroll
        for (int dn = 0; dn < 2; ++dn)
            vb[dn] = *(const bf16x8*)(&v_t[((h * 2 + fr) * 32 + dn * 16 + lrow) * 24 + quad * 8]);

        f32x4 ot[2][2];
        #pragma unroll
        for (int qm = 0; qm < 2; ++qm)
            #pragma unroll
            for (int dn = 0; dn < 2; ++dn)
                ot[qm][dn] = __builtin_amdgcn_mfma_f32_16x16x32_bf16(
                    pa[qm], vb[dn], (f32x4){0.f, 0.f, 0.f, 0.f}, 0, 0, 0);

        #pragma unroll
        for (int qm = 0; qm < 2; ++qm) {
            #pragma unroll
            for (int r2 = 0; r2 < 4; ++r2) {
                int q = qm * 16 + quad * 4 + r2;
                if (q < 22) {
                    float* op = out + (size_t)(tok0 + fr * 22 + q) * DM + h * 32;
                    op[lrow]      = ot[qm][0][r2];
                    op[16 + lrow] = ot[qm][1][r2];
                }
            }
        }
    }
}

extern "C" void kernel_launch(void* const* d_in, const int* in_sizes, int n_in,
                              void* d_out, int out_size, void* d_ws, size_t ws_size,
                              hipStream_t stream) {
    const float* x  = (const float*)d_in[0];
    const float* wq = (const float*)d_in[1];
    const float* bq = (const float*)d_in[2];
    const float* wk = (const float*)d_in[3];
    const float* bk = (const float*)d_in[4];
    const float* wv = (const float*)d_in[5];
    const float* bv = (const float*)d_in[6];

    char* ws = (char*)d_ws;
    float*          pewb = (float*)(ws + OFF_PEWB);
    unsigned short* wcan = (unsigned short*)(ws + OFF_WCAN);
    unsigned short* qkv  = (unsigned short*)(ws + OFF_QKV);

    wconv_kernel<<<dim3(32, 3), dim3(256), 0, stream>>>(wq, wk, wv, wcan);
    pewb_kernel<<<dim3(66), dim3(256), 0, stream>>>(wq, wk, wv, bq, bk, bv, pewb);
    qkv_gemm<<<dim3(TOKENS / BM), dim3(256), 0, stream>>>(x, wcan, pewb, qkv);
    attn_kernel<<<dim3(TOKENS / ABLK), dim3(256), 0, stream>>>(qkv, (float*)d_out);
}

// Round 8
// 296.310 us; speedup vs baseline: 1.5871x; 1.1573x over previous
//
#include <hip/hip_runtime.h>

#define TOKENS 90112
#define DM 256
#define NOUT 768
#define JOINTS 22

typedef __attribute__((ext_vector_type(8))) short bf16x8;
typedef __attribute__((ext_vector_type(4))) float f32x4;

__device__ __forceinline__ float b2f(unsigned short u) {
    union { unsigned int i; float f; } x; x.i = ((unsigned int)u) << 16; return x.f;
}
__device__ __forceinline__ unsigned short f2b(float f) {
    union { float f; unsigned int u; } x; x.f = f;
    unsigned int r = x.u + 0x7FFFu + ((x.u >> 16) & 1u);
    return (unsigned short)(r >> 16);
}

// ws layout
#define OFF_PEWB 0
#define OFF_WCAN (JOINTS * NOUT * 4)                 // 67584
#define OFF_QKV  (OFF_WCAN + 3 * DM * DM * 2)        // 460800

// ---------------- convert W (fp32 -> bf16), 3 matrices ----------------
__global__ __launch_bounds__(256) void wconv_kernel(const float* __restrict__ w0,
                                                    const float* __restrict__ w1,
                                                    const float* __restrict__ w2,
                                                    unsigned short* __restrict__ wcan)
{
    const float* w = (blockIdx.y == 0) ? w0 : (blockIdx.y == 1 ? w1 : w2);
    int i = (blockIdx.x * 256 + threadIdx.x) * 8;
    const float* s = w + i;
    union { uint4 v; float f[4]; } a, b;
    a.v = *(const uint4*)(s);
    b.v = *(const uint4*)(s + 4);
    union { uint4 v; unsigned short u[8]; } o;
    #pragma unroll
    for (int k = 0; k < 4; ++k) { o.u[k] = f2b(a.f[k]); o.u[4 + k] = f2b(b.f[k]); }
    *(uint4*)(wcan + blockIdx.y * (DM * DM) + i) = o.v;
}

// ---------------- PEWB[j,e] = bias[e] + sum_d pe[j,d] * W[e,d]  (fp32 inputs) ----------------
__global__ __launch_bounds__(256) void pewb_kernel(const float* __restrict__ wq,
                                                   const float* __restrict__ wk,
                                                   const float* __restrict__ wv,
                                                   const float* __restrict__ bq,
                                                   const float* __restrict__ bk,
                                                   const float* __restrict__ bv,
                                                   float* __restrict__ pewb)
{
    __shared__ float pe_s[DM];
    const int j   = blockIdx.x / 3;
    const int mat = blockIdx.x % 3;
    const int t = threadIdx.x;
    {
        int i = t >> 1;
        float div = __expf((float)(2 * i) * (-9.210340371976184f / 256.0f)); // -ln(10000)/256
        float ang = (float)j * div;
        pe_s[t] = (t & 1) ? cosf(ang) : sinf(ang);
    }
    __syncthreads();
    const float* w  = (mat == 0) ? wq : (mat == 1 ? wk : wv);
    const float* bb = (mat == 0) ? bq : (mat == 1 ? bk : bv);
    float acc = bb[t];
    const float* wr = w + (size_t)t * DM;
    #pragma unroll 8
    for (int d = 0; d < DM; ++d) acc += pe_s[d] * wr[d];
    pewb[j * NOUT + mat * DM + t] = acc;
}

// ---------------- QKV GEMM: exact r0 version (102 us verified) ----------------
#define BM 64
#define BN 128

__global__ __launch_bounds__(256) void qkv_gemm(const float* __restrict__ x,
                                                const unsigned short* __restrict__ wcan,
                                                const float* __restrict__ pewb,
                                                unsigned short* __restrict__ qkv)
{
    // As: 64 rows x 256 cols bf16, chunk-swizzled: chunk c stored at (c&24)|((c&7)^(row&7))
    // Bs: 128 rows x 64 cols bf16, chunk-swizzled: chunk c stored at c^(row&7)
    __shared__ __align__(16) unsigned short As[BM * 256];   // 32 KB
    __shared__ __align__(16) unsigned short Bs[BN * 64];    // 16 KB

    const int t    = threadIdx.x;
    const int m0   = blockIdx.x * BM;
    const int lane = t & 63;
    const int wave = t >> 6;
    const int wm   = (wave & 1) * 32;
    const int wn   = (wave >> 1) * 64;
    const int lrow = lane & 15;
    const int quad = lane >> 4;

    // stage full-K x tile, converting fp32 -> bf16 (8 chunks of 8 per thread)
    #pragma unroll
    for (int i = 0; i < 8; ++i) {
        int ch  = t + i * 256;          // 0..2047
        int row = ch >> 5, c = ch & 31;
        const float* src = x + (size_t)(m0 + row) * DM + c * 8;
        union { uint4 v; float f[4]; } a, b;
        a.v = *(const uint4*)(src);
        b.v = *(const uint4*)(src + 4);
        union { uint4 v; unsigned short u[8]; } o;
        #pragma unroll
        for (int k = 0; k < 4; ++k) { o.u[k] = f2b(a.f[k]); o.u[4 + k] = f2b(b.f[k]); }
        int cs = (c & 24) | ((c & 7) ^ (row & 7));
        *(uint4*)(&As[row * 256 + cs * 8]) = o.v;
    }

    for (int bn = 0; bn < 6; ++bn) {
        const unsigned short* wbase = wcan + (bn >> 1) * (DM * DM) + (bn & 1) * (BN * DM);

        f32x4 acc[2][4];
        #pragma unroll
        for (int mi = 0; mi < 2; ++mi)
            #pragma unroll
            for (int ni = 0; ni < 4; ++ni)
                acc[mi][ni] = (f32x4){0.f, 0.f, 0.f, 0.f};

        for (int k0 = 0; k0 < DM; k0 += 64) {
            __syncthreads();   // Bs readers done (and As staged, first iter)
            #pragma unroll
            for (int i = 0; i < 4; ++i) {
                int ch  = t + i * 256;      // 0..1023
                int row = ch >> 3, c = ch & 7;
                uint4 v = *(const uint4*)(&wbase[(size_t)row * DM + k0 + c * 8]);
                *(uint4*)(&Bs[row * 64 + ((c ^ (row & 7)) * 8)]) = v;
            }
            __syncthreads();
            #pragma unroll
            for (int kk = 0; kk < 64; kk += 32) {
                bf16x8 a[2], b[4];
                #pragma unroll
                for (int mi = 0; mi < 2; ++mi) {
                    int row = wm + mi * 16 + lrow;
                    int c   = ((k0 + kk) >> 3) + quad;
                    int cs  = (c & 24) | ((c & 7) ^ (row & 7));
                    a[mi] = *(const bf16x8*)(&As[row * 256 + cs * 8]);
                }
                #pragma unroll
                for (int ni = 0; ni < 4; ++ni) {
                    int row = wn + ni * 16 + lrow;
                    int c   = (kk >> 3) + quad;
                    b[ni] = *(const bf16x8*)(&Bs[row * 64 + ((c ^ (row & 7)) * 8)]);
                }
                #pragma unroll
                for (int mi = 0; mi < 2; ++mi)
                    #pragma unroll
                    for (int ni = 0; ni < 4; ++ni)
                        acc[mi][ni] = __builtin_amdgcn_mfma_f32_16x16x32_bf16(
                            a[mi], b[ni], acc[mi][ni], 0, 0, 0);
            }
        }

        // epilogue: add PEWB[joint], store bf16
        const int n0 = bn * BN;
        #pragma unroll
        for (int mi = 0; mi < 2; ++mi) {
            #pragma unroll
            for (int r = 0; r < 4; ++r) {
                int row   = wm + mi * 16 + quad * 4 + r;   // C row = (lane>>4)*4 + reg
                int token = m0 + row;
                int joint = token % JOINTS;
                const float* pw = pewb + joint * NOUT + n0;
                size_t obase = (size_t)token * NOUT + n0;
                #pragma unroll
                for (int ni = 0; ni < 4; ++ni) {
                    int col = wn + ni * 16 + lrow;         // C col = lane&15
                    qkv[obase + col] = f2b(acc[mi][ni][r] + pw[col]);
                }
            }
        }
    }
}

// ---------------- MFMA block-diagonal attention: block = 44 tokens (2 frames) ----------------
// (r7-verified, absmax 0.0359, est ~72 us). K staged row-major (stride 40); V staged
// transposed ([h*2+fr][d:32][k stride 24], pad cols zeroed); Q frags read from global.
// Wave-unit = (frame, head): S^T = mfma(K,Q), masked in-reg softmax (shfl_xor 16/32),
// P repacked via 16 shfls, O = mfma(P, V^T). 52.7 KB LDS -> 3 blocks/CU.
#define ABLK 44

__global__ __launch_bounds__(256) void attn_kernel(const unsigned short* __restrict__ qkv,
                                                   float* __restrict__ out)
{
    __shared__ __align__(16) unsigned short k_s[8 * ABLK * 40];       // 28160 B
    __shared__ __align__(16) unsigned short v_t[16 * 32 * 24 + 8];    // 24592 B

    const int t    = threadIdx.x;
    const int tok0 = blockIdx.x * ABLK;
    const int lane = t & 63;
    const int wave = t >> 6;
    const int lrow = lane & 15;
    const int quad = lane >> 4;

    // zero pad cols (k=22,23) of every v_t row + tail (disjoint from staged cols)
    for (int i = t; i < 16 * 32; i += 256)
        *(unsigned int*)(&v_t[i * 24 + 22]) = 0u;
    if (t < 4) ((unsigned int*)(&v_t[16 * 32 * 24]))[t] = 0u;

    // stage K rows (coalesced 16B chunks)
    for (int i = t; i < ABLK * 32; i += 256) {
        int r = i >> 5;          // token row 0..43
        int c = i & 31;          // 8-short chunk: h = c>>2, dchunk = c&3
        int h = c >> 2, dc = c & 3;
        uint4 v = *(const uint4*)(&qkv[(size_t)(tok0 + r) * NOUT + 256 + c * 8]);
        *(uint4*)(&k_s[(h * ABLK + r) * 40 + dc * 8]) = v;
    }
    // stage V transposed (u16 scatter into v_t[row=d][col=k])
    for (int i = t; i < ABLK * 32; i += 256) {
        int r = i >> 5;
        int c = i & 31;
        int h = c >> 2, dc = c & 3;
        int fr = r / 22, k = r - fr * 22;
        union { uint4 v; unsigned short u[8]; } w;
        w.v = *(const uint4*)(&qkv[(size_t)(tok0 + r) * NOUT + 512 + c * 8]);
        int base = ((h * 2 + fr) * 32 + dc * 8) * 24 + k;
        #pragma unroll
        for (int j = 0; j < 8; ++j) v_t[base + j * 24] = w.u[j];
    }
    __syncthreads();

    const float SC = 0.17677669529663688f;   // 1/sqrt(32)

    #pragma unroll 1
    for (int stp = 0; stp < 4; ++stp) {
        const int u4 = wave + stp * 4;       // 0..15
        const int fr = u4 & 1;
        const int h  = u4 >> 1;

        // S^T[k,q]: A = K rows (LDS), B = Q rows (global)
        bf16x8 ka[2], qb[2];
        #pragma unroll
        for (int km = 0; km < 2; ++km) {
            int kr = km * 16 + lrow; if (kr > 21) kr = 21;
            ka[km] = *(const bf16x8*)(&k_s[(h * ABLK + fr * 22 + kr) * 40 + quad * 8]);
        }
        #pragma unroll
        for (int qn = 0; qn < 2; ++qn) {
            int qr = qn * 16 + lrow; if (qr > 21) qr = 21;
            qb[qn] = *(const bf16x8*)(&qkv[(size_t)(tok0 + fr * 22 + qr) * NOUT + h * 32 + quad * 8]);
        }
        f32x4 st[2][2];
        #pragma unroll
        for (int km = 0; km < 2; ++km)
            #pragma unroll
            for (int qn = 0; qn < 2; ++qn)
                st[km][qn] = __builtin_amdgcn_mfma_f32_16x16x32_bf16(
                    ka[km], qb[qn], (f32x4){0.f, 0.f, 0.f, 0.f}, 0, 0, 0);

        // masked softmax per q (= lrow); lane holds k = km*16 + quad*4 + r2; scale by SC
        unsigned int u[2][2][2];
        #pragma unroll
        for (int qn = 0; qn < 2; ++qn) {
            float mx = -3.0e38f;
            #pragma unroll
            for (int r2 = 0; r2 < 4; ++r2) mx = fmaxf(mx, st[0][qn][r2] * SC);
            #pragma unroll
            for (int r2 = 0; r2 < 4; ++r2)
                if (16 + quad * 4 + r2 < 22) mx = fmaxf(mx, st[1][qn][r2] * SC);
            mx = fmaxf(mx, __shfl_xor(mx, 16));
            mx = fmaxf(mx, __shfl_xor(mx, 32));
            float p0[4], p1[4];
            float sum = 0.f;
            #pragma unroll
            for (int r2 = 0; r2 < 4; ++r2) { p0[r2] = __expf(st[0][qn][r2] * SC - mx); sum += p0[r2]; }
            #pragma unroll
            for (int r2 = 0; r2 < 4; ++r2) {
                float e = (16 + quad * 4 + r2 < 22) ? __expf(st[1][qn][r2] * SC - mx) : 0.f;
                p1[r2] = e; sum += e;
            }
            sum += __shfl_xor(sum, 16);
            sum += __shfl_xor(sum, 32);
            float inv = 1.f / sum;
            #pragma unroll
            for (int r2 = 0; r2 < 4; ++r2) { p0[r2] *= inv; p1[r2] *= inv; }
            u[qn][0][0] = (unsigned int)f2b(p0[0]) | ((unsigned int)f2b(p0[1]) << 16);
            u[qn][0][1] = (unsigned int)f2b(p0[2]) | ((unsigned int)f2b(p0[3]) << 16);
            u[qn][1][0] = (unsigned int)f2b(p1[0]) | ((unsigned int)f2b(p1[1]) << 16);
            u[qn][1][1] = (unsigned int)f2b(p1[2]) | ((unsigned int)f2b(p1[3]) << 16);
        }

        // repack P (C layout) -> A-frag layout (r5/r6-verified)
        bf16x8 pa[2];
        #pragma unroll
        for (int qm = 0; qm < 2; ++qm) {
            union { bf16x8 v; unsigned int w[4]; } au;
            #pragma unroll
            for (int j = 0; j < 4; ++j) {
                int src = lrow + 16 * ((quad & 1) * 2 + (j >> 1));
                unsigned int lo = (unsigned int)__shfl((int)u[qm][0][j & 1], src, 64);
                unsigned int hi = (unsigned int)__shfl((int)u[qm][1][j & 1], src, 64);
                au.w[j] = (quad < 2) ? lo : hi;
            }
            pa[qm] = au.v;
        }

        // O = P x V (V^T frags; pad/overhang reads are finite junk x P=0)
        bf16x8 vb[2];
        #pragma unroll
        for (int dn = 0; dn < 2; ++dn)
            vb[dn] = *(const bf16x8*)(&v_t[((h * 2 + fr) * 32 + dn * 16 + lrow) * 24 + quad * 8]);

        f32x4 ot[2][2];
        #pragma unroll
        for (int qm = 0; qm < 2; ++qm)
            #pragma unroll
            for (int dn = 0; dn < 2; ++dn)
                ot[qm][dn] = __builtin_amdgcn_mfma_f32_16x16x32_bf16(
                    pa[qm], vb[dn], (f32x4){0.f, 0.f, 0.f, 0.f}, 0, 0, 0);

        #pragma unroll
        for (int qm = 0; qm < 2; ++qm) {
            #pragma unroll
            for (int r2 = 0; r2 < 4; ++r2) {
                int q = qm * 16 + quad * 4 + r2;
                if (q < 22) {
                    float* op = out + (size_t)(tok0 + fr * 22 + q) * DM + h * 32;
                    op[lrow]      = ot[qm][0][r2];
                    op[16 + lrow] = ot[qm][1][r2];
                }
            }
        }
    }
}

extern "C" void kernel_launch(void* const* d_in, const int* in_sizes, int n_in,
                              void* d_out, int out_size, void* d_ws, size_t ws_size,
                              hipStream_t stream) {
    const float* x  = (const float*)d_in[0];
    const float* wq = (const float*)d_in[1];
    const float* bq = (const float*)d_in[2];
    const float* wk = (const float*)d_in[3];
    const float* bk = (const float*)d_in[4];
    const float* wv = (const float*)d_in[5];
    const float* bv = (const float*)d_in[6];

    char* ws = (char*)d_ws;
    float*          pewb = (float*)(ws + OFF_PEWB);
    unsigned short* wcan = (unsigned short*)(ws + OFF_WCAN);
    unsigned short* qkv  = (unsigned short*)(ws + OFF_QKV);

    wconv_kernel<<<dim3(32, 3), dim3(256), 0, stream>>>(wq, wk, wv, wcan);
    pewb_kernel<<<dim3(66), dim3(256), 0, stream>>>(wq, wk, wv, bq, bk, bv, pewb);
    qkv_gemm<<<dim3(TOKENS / BM), dim3(256), 0, stream>>>(x, wcan, pewb, qkv);
    attn_kernel<<<dim3(TOKENS / ABLK), dim3(256), 0, stream>>>(qkv, (float*)d_out);
}

// Round 9
// 291.425 us; speedup vs baseline: 1.6137x; 1.0168x over previous
//
#include <hip/hip_runtime.h>

#define TOKENS 90112
#define DM 256
#define NOUT 768
#define JOINTS 22

typedef __attribute__((ext_vector_type(8))) short bf16x8;
typedef __attribute__((ext_vector_type(4))) float f32x4;

__device__ __forceinline__ float b2f(unsigned short u) {
    union { unsigned int i; float f; } x; x.i = ((unsigned int)u) << 16; return x.f;
}
__device__ __forceinline__ unsigned short f2b(float f) {
    union { float f; unsigned int u; } x; x.f = f;
    unsigned int r = x.u + 0x7FFFu + ((x.u >> 16) & 1u);
    return (unsigned short)(r >> 16);
}

// async global->LDS, 16B per lane (dest = wave-uniform base + lane*16)
__device__ __forceinline__ void gl_lds16(const unsigned short* g, unsigned short* l) {
    __builtin_amdgcn_global_load_lds((const __attribute__((address_space(1))) unsigned int*)g,
                                     (__attribute__((address_space(3))) unsigned int*)l,
                                     16, 0, 0);
}

// ws layout
#define OFF_PEWB 0
#define OFF_WCAN (JOINTS * NOUT * 4)                 // 67584
#define OFF_QKV  (OFF_WCAN + 3 * DM * DM * 2)        // 460800

// ---------------- convert W (fp32 -> bf16), 3 matrices ----------------
__global__ __launch_bounds__(256) void wconv_kernel(const float* __restrict__ w0,
                                                    const float* __restrict__ w1,
                                                    const float* __restrict__ w2,
                                                    unsigned short* __restrict__ wcan)
{
    const float* w = (blockIdx.y == 0) ? w0 : (blockIdx.y == 1 ? w1 : w2);
    int i = (blockIdx.x * 256 + threadIdx.x) * 8;
    const float* s = w + i;
    union { uint4 v; float f[4]; } a, b;
    a.v = *(const uint4*)(s);
    b.v = *(const uint4*)(s + 4);
    union { uint4 v; unsigned short u[8]; } o;
    #pragma unroll
    for (int k = 0; k < 4; ++k) { o.u[k] = f2b(a.f[k]); o.u[4 + k] = f2b(b.f[k]); }
    *(uint4*)(wcan + blockIdx.y * (DM * DM) + i) = o.v;
}

// ---------------- PEWB[j,e] = bias[e] + sum_d pe[j,d] * W[e,d]  (fp32 inputs) ----------------
__global__ __launch_bounds__(256) void pewb_kernel(const float* __restrict__ wq,
                                                   const float* __restrict__ wk,
                                                   const float* __restrict__ wv,
                                                   const float* __restrict__ bq,
                                                   const float* __restrict__ bk,
                                                   const float* __restrict__ bv,
                                                   float* __restrict__ pewb)
{
    __shared__ float pe_s[DM];
    const int j   = blockIdx.x / 3;
    const int mat = blockIdx.x % 3;
    const int t = threadIdx.x;
    {
        int i = t >> 1;
        float div = __expf((float)(2 * i) * (-9.210340371976184f / 256.0f)); // -ln(10000)/256
        float ang = (float)j * div;
        pe_s[t] = (t & 1) ? cosf(ang) : sinf(ang);
    }
    __syncthreads();
    const float* w  = (mat == 0) ? wq : (mat == 1 ? wk : wv);
    const float* bb = (mat == 0) ? bq : (mat == 1 ? bk : bv);
    float acc = bb[t];
    const float* wr = w + (size_t)t * DM;
    #pragma unroll 8
    for (int d = 0; d < DM; ++d) acc += pe_s[d] * wr[d];
    pewb[j * NOUT + mat * DM + t] = acc;
}

// ---------------- QKV GEMM: r0 structure; Bs staged via global_load_lds ----------------
// Rule-21 pattern: LINEAR LDS dest (wave base + lane*16) + INVERSE-swizzled global
// source (XOR involution: same c^(row&7)) + swizzle on read (unchanged read side).
#define BM 64
#define BN 128

__global__ __launch_bounds__(256) void qkv_gemm(const float* __restrict__ x,
                                                const unsigned short* __restrict__ wcan,
                                                const float* __restrict__ pewb,
                                                unsigned short* __restrict__ qkv)
{
    // As: 64 rows x 256 cols bf16, chunk-swizzled: chunk c stored at (c&24)|((c&7)^(row&7))
    // Bs: 128 rows x 64 cols bf16, chunk-swizzled: chunk c stored at c^(row&7)
    __shared__ __align__(16) unsigned short As[BM * 256];   // 32 KB
    __shared__ __align__(16) unsigned short Bs[BN * 64];    // 16 KB

    const int t    = threadIdx.x;
    const int m0   = blockIdx.x * BM;
    const int lane = t & 63;
    const int wave = t >> 6;
    const int wm   = (wave & 1) * 32;
    const int wn   = (wave >> 1) * 64;
    const int lrow = lane & 15;
    const int quad = lane >> 4;

    // stage full-K x tile, converting fp32 -> bf16 (8 chunks of 8 per thread)
    #pragma unroll
    for (int i = 0; i < 8; ++i) {
        int ch  = t + i * 256;          // 0..2047
        int row = ch >> 5, c = ch & 31;
        const float* src = x + (size_t)(m0 + row) * DM + c * 8;
        union { uint4 v; float f[4]; } a, b;
        a.v = *(const uint4*)(src);
        b.v = *(const uint4*)(src + 4);
        union { uint4 v; unsigned short u[8]; } o;
        #pragma unroll
        for (int k = 0; k < 4; ++k) { o.u[k] = f2b(a.f[k]); o.u[4 + k] = f2b(b.f[k]); }
        int cs = (c & 24) | ((c & 7) ^ (row & 7));
        *(uint4*)(&As[row * 256 + cs * 8]) = o.v;
    }

    for (int bn = 0; bn < 6; ++bn) {
        const unsigned short* wbase = wcan + (bn >> 1) * (DM * DM) + (bn & 1) * (BN * DM);

        f32x4 acc[2][4];
        #pragma unroll
        for (int mi = 0; mi < 2; ++mi)
            #pragma unroll
            for (int ni = 0; ni < 4; ++ni)
                acc[mi][ni] = (f32x4){0.f, 0.f, 0.f, 0.f};

        for (int k0 = 0; k0 < DM; k0 += 64) {
            __syncthreads();   // Bs readers done (and As staged, first iter)
            // async stage: lane's linear chunk ch gets global chunk c^(row&7)
            #pragma unroll
            for (int i = 0; i < 4; ++i) {
                int ch  = t + i * 256;      // 0..1023
                int row = ch >> 3, c = ch & 7;
                const unsigned short* gsrc = wbase + (size_t)row * DM + k0 + ((c ^ (row & 7)) * 8);
                gl_lds16(gsrc, &Bs[(i * 256 + wave * 64) * 8]);
            }
            __syncthreads();   // vmcnt(0) drained by compiler before barrier
            #pragma unroll
            for (int kk = 0; kk < 64; kk += 32) {
                bf16x8 a[2], b[4];
                #pragma unroll
                for (int mi = 0; mi < 2; ++mi) {
                    int row = wm + mi * 16 + lrow;
                    int c   = ((k0 + kk) >> 3) + quad;
                    int cs  = (c & 24) | ((c & 7) ^ (row & 7));
                    a[mi] = *(const bf16x8*)(&As[row * 256 + cs * 8]);
                }
                #pragma unroll
                for (int ni = 0; ni < 4; ++ni) {
                    int row = wn + ni * 16 + lrow;
                    int c   = (kk >> 3) + quad;
                    b[ni] = *(const bf16x8*)(&Bs[row * 64 + ((c ^ (row & 7)) * 8)]);
                }
                #pragma unroll
                for (int mi = 0; mi < 2; ++mi)
                    #pragma unroll
                    for (int ni = 0; ni < 4; ++ni)
                        acc[mi][ni] = __builtin_amdgcn_mfma_f32_16x16x32_bf16(
                            a[mi], b[ni], acc[mi][ni], 0, 0, 0);
            }
        }

        // epilogue: add PEWB[joint], store bf16
        const int n0 = bn * BN;
        #pragma unroll
        for (int mi = 0; mi < 2; ++mi) {
            #pragma unroll
            for (int r = 0; r < 4; ++r) {
                int row   = wm + mi * 16 + quad * 4 + r;   // C row = (lane>>4)*4 + reg
                int token = m0 + row;
                int joint = token % JOINTS;
                const float* pw = pewb + joint * NOUT + n0;
                size_t obase = (size_t)token * NOUT + n0;
                #pragma unroll
                for (int ni = 0; ni < 4; ++ni) {
                    int col = wn + ni * 16 + lrow;         // C col = lane&15
                    qkv[obase + col] = f2b(acc[mi][ni][r] + pw[col]);
                }
            }
        }
    }
}

// ---------------- MFMA block-diagonal attention: block = 44 tokens (2 frames) ----------------
// (r7-verified, absmax 0.0359, est ~72 us). K staged row-major (stride 40); V staged
// transposed ([h*2+fr][d:32][k stride 24], pad cols zeroed); Q frags read from global.
// Wave-unit = (frame, head): S^T = mfma(K,Q), masked in-reg softmax (shfl_xor 16/32),
// P repacked via 16 shfls, O = mfma(P, V^T). 52.7 KB LDS -> 3 blocks/CU.
#define ABLK 44

__global__ __launch_bounds__(256) void attn_kernel(const unsigned short* __restrict__ qkv,
                                                   float* __restrict__ out)
{
    __shared__ __align__(16) unsigned short k_s[8 * ABLK * 40];       // 28160 B
    __shared__ __align__(16) unsigned short v_t[16 * 32 * 24 + 8];    // 24592 B

    const int t    = threadIdx.x;
    const int tok0 = blockIdx.x * ABLK;
    const int lane = t & 63;
    const int wave = t >> 6;
    const int lrow = lane & 15;
    const int quad = lane >> 4;

    // zero pad cols (k=22,23) of every v_t row + tail (disjoint from staged cols)
    for (int i = t; i < 16 * 32; i += 256)
        *(unsigned int*)(&v_t[i * 24 + 22]) = 0u;
    if (t < 4) ((unsigned int*)(&v_t[16 * 32 * 24]))[t] = 0u;

    // stage K rows (coalesced 16B chunks)
    for (int i = t; i < ABLK * 32; i += 256) {
        int r = i >> 5;          // token row 0..43
        int c = i & 31;          // 8-short chunk: h = c>>2, dchunk = c&3
        int h = c >> 2, dc = c & 3;
        uint4 v = *(const uint4*)(&qkv[(size_t)(tok0 + r) * NOUT + 256 + c * 8]);
        *(uint4*)(&k_s[(h * ABLK + r) * 40 + dc * 8]) = v;
    }
    // stage V transposed (u16 scatter into v_t[row=d][col=k])
    for (int i = t; i < ABLK * 32; i += 256) {
        int r = i >> 5;
        int c = i & 31;
        int h = c >> 2, dc = c & 3;
        int fr = r / 22, k = r - fr * 22;
        union { uint4 v; unsigned short u[8]; } w;
        w.v = *(const uint4*)(&qkv[(size_t)(tok0 + r) * NOUT + 512 + c * 8]);
        int base = ((h * 2 + fr) * 32 + dc * 8) * 24 + k;
        #pragma unroll
        for (int j = 0; j < 8; ++j) v_t[base + j * 24] = w.u[j];
    }
    __syncthreads();

    const float SC = 0.17677669529663688f;   // 1/sqrt(32)

    #pragma unroll 1
    for (int stp = 0; stp < 4; ++stp) {
        const int u4 = wave + stp * 4;       // 0..15
        const int fr = u4 & 1;
        const int h  = u4 >> 1;

        // S^T[k,q]: A = K rows (LDS), B = Q rows (global)
        bf16x8 ka[2], qb[2];
        #pragma unroll
        for (int km = 0; km < 2; ++km) {
            int kr = km * 16 + lrow; if (kr > 21) kr = 21;
            ka[km] = *(const bf16x8*)(&k_s[(h * ABLK + fr * 22 + kr) * 40 + quad * 8]);
        }
        #pragma unroll
        for (int qn = 0; qn < 2; ++qn) {
            int qr = qn * 16 + lrow; if (qr > 21) qr = 21;
            qb[qn] = *(const bf16x8*)(&qkv[(size_t)(tok0 + fr * 22 + qr) * NOUT + h * 32 + quad * 8]);
        }
        f32x4 st[2][2];
        #pragma unroll
        for (int km = 0; km < 2; ++km)
            #pragma unroll
            for (int qn = 0; qn < 2; ++qn)
                st[km][qn] = __builtin_amdgcn_mfma_f32_16x16x32_bf16(
                    ka[km], qb[qn], (f32x4){0.f, 0.f, 0.f, 0.f}, 0, 0, 0);

        // masked softmax per q (= lrow); lane holds k = km*16 + quad*4 + r2; scale by SC
        unsigned int u[2][2][2];
        #pragma unroll
        for (int qn = 0; qn < 2; ++qn) {
            float mx = -3.0e38f;
            #pragma unroll
            for (int r2 = 0; r2 < 4; ++r2) mx = fmaxf(mx, st[0][qn][r2] * SC);
            #pragma unroll
            for (int r2 = 0; r2 < 4; ++r2)
                if (16 + quad * 4 + r2 < 22) mx = fmaxf(mx, st[1][qn][r2] * SC);
            mx = fmaxf(mx, __shfl_xor(mx, 16));
            mx = fmaxf(mx, __shfl_xor(mx, 32));
            float p0[4], p1[4];
            float sum = 0.f;
            #pragma unroll
            for (int r2 = 0; r2 < 4; ++r2) { p0[r2] = __expf(st[0][qn][r2] * SC - mx); sum += p0[r2]; }
            #pragma unroll
            for (int r2 = 0; r2 < 4; ++r2) {
                float e = (16 + quad * 4 + r2 < 22) ? __expf(st[1][qn][r2] * SC - mx) : 0.f;
                p1[r2] = e; sum += e;
            }
            sum += __shfl_xor(sum, 16);
            sum += __shfl_xor(sum, 32);
            float inv = 1.f / sum;
            #pragma unroll
            for (int r2 = 0; r2 < 4; ++r2) { p0[r2] *= inv; p1[r2] *= inv; }
            u[qn][0][0] = (unsigned int)f2b(p0[0]) | ((unsigned int)f2b(p0[1]) << 16);
            u[qn][0][1] = (unsigned int)f2b(p0[2]) | ((unsigned int)f2b(p0[3]) << 16);
            u[qn][1][0] = (unsigned int)f2b(p1[0]) | ((unsigned int)f2b(p1[1]) << 16);
            u[qn][1][1] = (unsigned int)f2b(p1[2]) | ((unsigned int)f2b(p1[3]) << 16);
        }

        // repack P (C layout) -> A-frag layout (r5/r6-verified)
        bf16x8 pa[2];
        #pragma unroll
        for (int qm = 0; qm < 2; ++qm) {
            union { bf16x8 v; unsigned int w[4]; } au;
            #pragma unroll
            for (int j = 0; j < 4; ++j) {
                int src = lrow + 16 * ((quad & 1) * 2 + (j >> 1));
                unsigned int lo = (unsigned int)__shfl((int)u[qm][0][j & 1], src, 64);
                unsigned int hi = (unsigned int)__shfl((int)u[qm][1][j & 1], src, 64);
                au.w[j] = (quad < 2) ? lo : hi;
            }
            pa[qm] = au.v;
        }

        // O = P x V (V^T frags; pad/overhang reads are finite junk x P=0)
        bf16x8 vb[2];
        #pragma unroll
        for (int dn = 0; dn < 2; ++dn)
            vb[dn] = *(const bf16x8*)(&v_t[((h * 2 + fr) * 32 + dn * 16 + lrow) * 24 + quad * 8]);

        f32x4 ot[2][2];
        #pragma unroll
        for (int qm = 0; qm < 2; ++qm)
            #pragma unroll
            for (int dn = 0; dn < 2; ++dn)
                ot[qm][dn] = __builtin_amdgcn_mfma_f32_16x16x32_bf16(
                    pa[qm], vb[dn], (f32x4){0.f, 0.f, 0.f, 0.f}, 0, 0, 0);

        #pragma unroll
        for (int qm = 0; qm < 2; ++qm) {
            #pragma unroll
            for (int r2 = 0; r2 < 4; ++r2) {
                int q = qm * 16 + quad * 4 + r2;
                if (q < 22) {
                    float* op = out + (size_t)(tok0 + fr * 22 + q) * DM + h * 32;
                    op[lrow]      = ot[qm][0][r2];
                    op[16 + lrow] = ot[qm][1][r2];
                }
            }
        }
    }
}

extern "C" void kernel_launch(void* const* d_in, const int* in_sizes, int n_in,
                              void* d_out, int out_size, void* d_ws, size_t ws_size,
                              hipStream_t stream) {
    const float* x  = (const float*)d_in[0];
    const float* wq = (const float*)d_in[1];
    const float* bq = (const float*)d_in[2];
    const float* wk = (const float*)d_in[3];
    const float* bk = (const float*)d_in[4];
    const float* wv = (const float*)d_in[5];
    const float* bv = (const float*)d_in[6];

    char* ws = (char*)d_ws;
    float*          pewb = (float*)(ws + OFF_PEWB);
    unsigned short* wcan = (unsigned short*)(ws + OFF_WCAN);
    unsigned short* qkv  = (unsigned short*)(ws + OFF_QKV);

    wconv_kernel<<<dim3(32, 3), dim3(256), 0, stream>>>(wq, wk, wv, wcan);
    pewb_kernel<<<dim3(66), dim3(256), 0, stream>>>(wq, wk, wv, bq, bk, bv, pewb);
    qkv_gemm<<<dim3(TOKENS / BM), dim3(256), 0, stream>>>(x, wcan, pewb, qkv);
    attn_kernel<<<dim3(TOKENS / ABLK), dim3(256), 0, stream>>>(qkv, (float*)d_out);
}